// Round 10
// baseline (75.054 us; speedup 1.0000x reference)
//
#include <hip/hip_runtime.h>
#include <hip/hip_fp16.h>

// NCC (local normalized cross-correlation) loss, 9x9x9 window, zero-pad.
// Volume: [1,1,128,160,192] f32. Output: scalar f32 = 1 - mean(cc).
//
// R10 = R9 (channel-packed fp16 intermediates, 3 passes) +
//   - sliding-window state kept as packed __half2 (v_pk_add_f16 add/sub:
//     no unpack/repack in the hot loops; pass2 stores packed S directly)
//   - finalize fused into pass3 (last-block ticket), one launch fewer.
// Layout per pixel-pair: ch0..3 (I,J,I2,J2) = uint4 (4x half2), ch4 (IJ) = u32.
// ws: Aq 31.5MB | Bq 31.5MB | As 7.9MB | Bs 7.9MB | acc | counter.

#define D_ 128
#define H_ 160
#define W_ 192
#define WP_ (W_ / 2)               // 96 pairs per line
#define HW_ (H_ * W_)
#define HWP_ (HW_ / 2)             // 15360 pairs per d-slice
#define N_ (D_ * H_ * W_)
#define NP_ (N_ / 2)               // 1,966,080 pairs total
#define WIN_INV (1.0f / 729.0f)
#define HR2 10                     // h-run length in pass2 (16 chunks)
#define CH3 8                      // d-run length in pass3 (16 chunks)
#define NBLK3 ((HWP_ / 256) * (D_ / CH3))   // 960

union U32H2 { unsigned u; __half2 h; };
__device__ __forceinline__ __half2 u2h(unsigned u) { U32H2 x; x.u = u; return x.h; }
__device__ __forceinline__ unsigned h2u(__half2 h) { U32H2 x; x.h = h; return x.u; }
__device__ __forceinline__ unsigned pack2(float x, float y) {
    return h2u(__float22half2_rn(make_float2(x, y)));
}

// ---------------- pass1: W-axis box sum -> packed A ------------------------
__global__ __launch_bounds__(256) void ncc_pass1(const float* __restrict__ I,
                                                 const float* __restrict__ J,
                                                 uint4* __restrict__ Aq,
                                                 unsigned* __restrict__ As,
                                                 float* __restrict__ acc,
                                                 unsigned* __restrict__ ctr) {
    __shared__ float sI[2 * W_];
    __shared__ float sJ[2 * W_];
    const int t = threadIdx.x;
    const int line0 = blockIdx.x * 2;
    const int base = line0 * W_;
    sI[t] = I[base + t];
    sJ[t] = J[base + t];
    if (t < 2 * W_ - 256) { sI[t + 256] = I[base + t + 256]; sJ[t + 256] = J[base + t + 256]; }
    if (blockIdx.x == 0 && t == 0) { *acc = 0.0f; *ctr = 0u; }
    __syncthreads();
    if (t >= 2 * WP_) return;
    const int ll = t / WP_;
    const int wp = t % WP_;
    const int w0 = 2 * wp;
    const float* a_ = sI + ll * W_;
    const float* b_ = sJ + ll * W_;
    float s1a = 0, s2a = 0, s3a = 0, s4a = 0, s5a = 0;
    float s1b = 0, s2b = 0, s3b = 0, s4b = 0, s5b = 0;
#pragma unroll
    for (int j = -4; j <= 5; ++j) {
        int idx = w0 + j;
        float a = 0.f, b = 0.f;
        if (idx >= 0 && idx < W_) { a = a_[idx]; b = b_[idx]; }
        float p3 = a * a, p4 = b * b, p5 = a * b;
        if (j <= 4) { s1a += a; s2a += b; s3a += p3; s4a += p4; s5a += p5; }
        if (j >= -3) { s1b += a; s2b += b; s3b += p3; s4b += p4; s5b += p5; }
    }
    const size_t o = (size_t)(line0 + ll) * WP_ + wp;
    Aq[o] = make_uint4(pack2(s1a, s1b), pack2(s2a, s2b),
                       pack2(s3a, s3b), pack2(s4a, s4b));
    As[o] = pack2(s5a, s5b);
}

// ---------------- pass2: H-axis box sum, packed-half FIFO ------------------
__global__ __launch_bounds__(256) void ncc_pass2(const uint4* __restrict__ Aq,
                                                 const unsigned* __restrict__ As,
                                                 uint4* __restrict__ Bq,
                                                 unsigned* __restrict__ Bs) {
    const int t = blockIdx.x * 256 + threadIdx.x;   // < 128*16*96 = 196608
    const int wp = t % WP_;
    const int r = t / WP_;
    const int hc = r & 15;
    const int d = r >> 4;
    const size_t cb = (size_t)d * (H_ * WP_) + wp;
    const uint4* aq = Aq + cb;
    const unsigned* as_ = As + cb;
    uint4* bq = Bq + cb;
    unsigned* bs = Bs + cb;
    const int h0 = hc * HR2;

    uint4 fq[9]; unsigned fs[9];
    const __half2 z = __float2half2_rn(0.f);
    __half2 S0 = z, S1 = z, S2 = z, S3 = z, S4 = z;
#pragma unroll
    for (int j = 0; j < 9; ++j) {
        int hh = h0 - 4 + j;
        uint4 q = make_uint4(0u, 0u, 0u, 0u); unsigned sv = 0u;
        if ((unsigned)hh < (unsigned)H_) {
            q = aq[(size_t)hh * WP_]; sv = as_[(size_t)hh * WP_];
        }
        fq[j] = q; fs[j] = sv;
        S0 = __hadd2(S0, u2h(q.x)); S1 = __hadd2(S1, u2h(q.y));
        S2 = __hadd2(S2, u2h(q.z)); S3 = __hadd2(S3, u2h(q.w));
        S4 = __hadd2(S4, u2h(sv));
    }
#pragma unroll
    for (int i = 0; i < HR2; ++i) {
        const int h = h0 + i;
        bq[(size_t)h * WP_] = make_uint4(h2u(S0), h2u(S1), h2u(S2), h2u(S3));
        bs[(size_t)h * WP_] = h2u(S4);
        if (i + 1 < HR2) {
            int hh = h + 5;
            uint4 q = make_uint4(0u, 0u, 0u, 0u); unsigned sv = 0u;
            if (hh < H_) { q = aq[(size_t)hh * WP_]; sv = as_[(size_t)hh * WP_]; }
            S0 = __hadd2(__hsub2(S0, u2h(fq[0].x)), u2h(q.x));
            S1 = __hadd2(__hsub2(S1, u2h(fq[0].y)), u2h(q.y));
            S2 = __hadd2(__hsub2(S2, u2h(fq[0].z)), u2h(q.z));
            S3 = __hadd2(__hsub2(S3, u2h(fq[0].w)), u2h(q.w));
            S4 = __hadd2(__hsub2(S4, u2h(fs[0])), u2h(sv));
#pragma unroll
            for (int j = 0; j < 8; ++j) { fq[j] = fq[j + 1]; fs[j] = fs[j + 1]; }
            fq[8] = q; fs[8] = sv;
        }
    }
}

// ------- pass3: D-axis box sum + cc + reduce + fused finalize --------------
__global__ __launch_bounds__(256) void ncc_pass3(const uint4* __restrict__ Bq,
                                                 const unsigned* __restrict__ Bs,
                                                 float* __restrict__ acc,
                                                 unsigned* __restrict__ ctr,
                                                 float* __restrict__ out) {
    const int pp = (blockIdx.x % (HWP_ / 256)) * 256 + threadIdx.x;
    const int d0 = (blockIdx.x / (HWP_ / 256)) * CH3;
    const uint4* bq = Bq + pp;
    const unsigned* bs = Bs + pp;

    uint4 fq[9]; unsigned fs[9];
    const __half2 z = __float2half2_rn(0.f);
    __half2 S0 = z, S1 = z, S2 = z, S3 = z, S4 = z;
#pragma unroll
    for (int j = 0; j < 9; ++j) {
        int dd = d0 - 4 + j;
        uint4 q = make_uint4(0u, 0u, 0u, 0u); unsigned sv = 0u;
        if ((unsigned)dd < (unsigned)D_) {
            q = bq[(size_t)dd * HWP_]; sv = bs[(size_t)dd * HWP_];
        }
        fq[j] = q; fs[j] = sv;
        S0 = __hadd2(S0, u2h(q.x)); S1 = __hadd2(S1, u2h(q.y));
        S2 = __hadd2(S2, u2h(q.z)); S3 = __hadd2(S3, u2h(q.w));
        S4 = __hadd2(S4, u2h(sv));
    }
    float sum = 0.f;
#pragma unroll
    for (int i = 0; i < CH3; ++i) {
        const float2 s0 = __half22float2(S0), s1 = __half22float2(S1),
                     s2 = __half22float2(S2), s3 = __half22float2(S3),
                     s4 = __half22float2(S4);
        {
            float cr = s4.x - s1.x * s0.x * WIN_INV;
            float Iv = s2.x - s0.x * s0.x * WIN_INV;
            float Jv = s3.x - s1.x * s1.x * WIN_INV;
            sum += cr * cr / (Iv * Jv + 1e-5f);
        }
        {
            float cr = s4.y - s1.y * s0.y * WIN_INV;
            float Iv = s2.y - s0.y * s0.y * WIN_INV;
            float Jv = s3.y - s1.y * s1.y * WIN_INV;
            sum += cr * cr / (Iv * Jv + 1e-5f);
        }
        if (i + 1 < CH3) {
            int dl = d0 + i + 5;
            uint4 q = make_uint4(0u, 0u, 0u, 0u); unsigned sv = 0u;
            if (dl < D_) { q = bq[(size_t)dl * HWP_]; sv = bs[(size_t)dl * HWP_]; }
            S0 = __hadd2(__hsub2(S0, u2h(fq[0].x)), u2h(q.x));
            S1 = __hadd2(__hsub2(S1, u2h(fq[0].y)), u2h(q.y));
            S2 = __hadd2(__hsub2(S2, u2h(fq[0].z)), u2h(q.z));
            S3 = __hadd2(__hsub2(S3, u2h(fq[0].w)), u2h(q.w));
            S4 = __hadd2(__hsub2(S4, u2h(fs[0])), u2h(sv));
#pragma unroll
            for (int j = 0; j < 8; ++j) { fq[j] = fq[j + 1]; fs[j] = fs[j + 1]; }
            fq[8] = q; fs[8] = sv;
        }
    }

    for (int off = 32; off; off >>= 1) sum += __shfl_down(sum, off, 64);
    __shared__ float wsum[4];
    const int lane = threadIdx.x & 63, wv = threadIdx.x >> 6;
    if (lane == 0) wsum[wv] = sum;
    __syncthreads();
    if (threadIdx.x == 0) {
        atomicAdd(acc, wsum[0] + wsum[1] + wsum[2] + wsum[3]);
        __threadfence();
        unsigned t = atomicAdd(ctr, 1u);
        if (t == NBLK3 - 1) {                     // last block: finalize
            float v = atomicAdd(acc, 0.0f);       // device-scope read of total
            out[0] = 1.0f - v * (1.0f / (float)N_);
        }
    }
}

extern "C" void kernel_launch(void* const* d_in, const int* in_sizes, int n_in,
                              void* d_out, int out_size, void* d_ws, size_t ws_size,
                              hipStream_t stream) {
    const float* I = (const float*)d_in[0];   // y_true
    const float* J = (const float*)d_in[1];   // y_pred
    char* w = (char*)d_ws;
    uint4* Aq = (uint4*)w;                                 // 31.46 MB
    uint4* Bq = (uint4*)(w + (size_t)NP_ * 16);            // 31.46 MB
    unsigned* As = (unsigned*)(w + (size_t)NP_ * 32);      // 7.86 MB
    unsigned* Bs = (unsigned*)(w + (size_t)NP_ * 36);      // 7.86 MB
    float* acc = (float*)(w + (size_t)NP_ * 40);
    unsigned* ctr = (unsigned*)(w + (size_t)NP_ * 40 + 4);
    float* out = (float*)d_out;

    ncc_pass1<<<D_ * H_ / 2, 256, 0, stream>>>(I, J, Aq, As, acc, ctr);
    ncc_pass2<<<(D_ * 16 * WP_) / 256, 256, 0, stream>>>(Aq, As, Bq, Bs);
    ncc_pass3<<<NBLK3, 256, 0, stream>>>(Bq, Bs, acc, ctr, out);
}

// Round 11
// 55.130 us; speedup vs baseline: 1.3614x; 1.3614x over previous
//
#include <hip/hip_runtime.h>
#include <hip/hip_fp16.h>

// NCC (local normalized cross-correlation) loss, 9x9x9 window, zero-pad.
// Volume: [1,1,128,160,192] f32. Output: scalar f32 = 1 - mean(cc).
//
// R11 = R9 structure (channel-packed fp16 intermediates, 4 launches):
//   pass1: W-sums -> Aq/As (packed stores).                     [R9]
//   pass2: H-sums Aq/As -> Bq/Bs, packed __half2 pk-arith FIFO. [R10 - keep]
//   pass3: D-sums + cc + reduce, f32 state + uint4 FIFO.        [R9 - revert]
//   finalize: separate kernel (no threadfence in pass3).        [R9 - revert]
// Layout per pixel-pair: ch0..3 (I,J,I2,J2) = uint4 (4x half2), ch4 (IJ) = u32.
// ws: Aq 31.5MB | Bq 31.5MB | As 7.9MB | Bs 7.9MB | acc.

#define D_ 128
#define H_ 160
#define W_ 192
#define WP_ (W_ / 2)               // 96 pairs per line
#define HW_ (H_ * W_)
#define HWP_ (HW_ / 2)             // 15360 pairs per d-slice
#define N_ (D_ * H_ * W_)
#define NP_ (N_ / 2)               // 1,966,080 pairs total
#define WIN_INV (1.0f / 729.0f)
#define HR2 10                     // h-run length in pass2 (16 chunks)
#define CH3 8                      // d-run length in pass3 (16 chunks)

union U32H2 { unsigned u; __half2 h; };
__device__ __forceinline__ __half2 u2h(unsigned u) { U32H2 x; x.u = u; return x.h; }
__device__ __forceinline__ unsigned h2u(__half2 h) { U32H2 x; x.h = h; return x.u; }
__device__ __forceinline__ unsigned pack2(float x, float y) {
    return h2u(__float22half2_rn(make_float2(x, y)));
}
__device__ __forceinline__ float2 unpack2(unsigned u) {
    return __half22float2(u2h(u));
}

__device__ __forceinline__ void addU(float2 S[5], const uint4& q, unsigned sv) {
    float2 v0 = unpack2(q.x), v1 = unpack2(q.y), v2 = unpack2(q.z),
           v3 = unpack2(q.w), v4 = unpack2(sv);
    S[0].x += v0.x; S[0].y += v0.y;
    S[1].x += v1.x; S[1].y += v1.y;
    S[2].x += v2.x; S[2].y += v2.y;
    S[3].x += v3.x; S[3].y += v3.y;
    S[4].x += v4.x; S[4].y += v4.y;
}
__device__ __forceinline__ void subU(float2 S[5], const uint4& q, unsigned sv) {
    float2 v0 = unpack2(q.x), v1 = unpack2(q.y), v2 = unpack2(q.z),
           v3 = unpack2(q.w), v4 = unpack2(sv);
    S[0].x -= v0.x; S[0].y -= v0.y;
    S[1].x -= v1.x; S[1].y -= v1.y;
    S[2].x -= v2.x; S[2].y -= v2.y;
    S[3].x -= v3.x; S[3].y -= v3.y;
    S[4].x -= v4.x; S[4].y -= v4.y;
}

// ---------------- pass1: W-axis box sum -> packed A ------------------------
__global__ __launch_bounds__(256) void ncc_pass1(const float* __restrict__ I,
                                                 const float* __restrict__ J,
                                                 uint4* __restrict__ Aq,
                                                 unsigned* __restrict__ As,
                                                 float* __restrict__ acc) {
    __shared__ float sI[2 * W_];
    __shared__ float sJ[2 * W_];
    const int t = threadIdx.x;
    const int line0 = blockIdx.x * 2;
    const int base = line0 * W_;
    sI[t] = I[base + t];
    sJ[t] = J[base + t];
    if (t < 2 * W_ - 256) { sI[t + 256] = I[base + t + 256]; sJ[t + 256] = J[base + t + 256]; }
    if (blockIdx.x == 0 && t == 0) *acc = 0.0f;
    __syncthreads();
    if (t >= 2 * WP_) return;
    const int ll = t / WP_;
    const int wp = t % WP_;
    const int w0 = 2 * wp;
    const float* a_ = sI + ll * W_;
    const float* b_ = sJ + ll * W_;
    float s1a = 0, s2a = 0, s3a = 0, s4a = 0, s5a = 0;
    float s1b = 0, s2b = 0, s3b = 0, s4b = 0, s5b = 0;
#pragma unroll
    for (int j = -4; j <= 5; ++j) {
        int idx = w0 + j;
        float a = 0.f, b = 0.f;
        if (idx >= 0 && idx < W_) { a = a_[idx]; b = b_[idx]; }
        float p3 = a * a, p4 = b * b, p5 = a * b;
        if (j <= 4) { s1a += a; s2a += b; s3a += p3; s4a += p4; s5a += p5; }
        if (j >= -3) { s1b += a; s2b += b; s3b += p3; s4b += p4; s5b += p5; }
    }
    const size_t o = (size_t)(line0 + ll) * WP_ + wp;
    Aq[o] = make_uint4(pack2(s1a, s1b), pack2(s2a, s2b),
                       pack2(s3a, s3b), pack2(s4a, s4b));
    As[o] = pack2(s5a, s5b);
}

// ---------------- pass2: H-axis box sum, packed-half pk FIFO ---------------
__global__ __launch_bounds__(256) void ncc_pass2(const uint4* __restrict__ Aq,
                                                 const unsigned* __restrict__ As,
                                                 uint4* __restrict__ Bq,
                                                 unsigned* __restrict__ Bs) {
    const int t = blockIdx.x * 256 + threadIdx.x;   // < 128*16*96 = 196608
    const int wp = t % WP_;
    const int r = t / WP_;
    const int hc = r & 15;
    const int d = r >> 4;
    const size_t cb = (size_t)d * (H_ * WP_) + wp;
    const uint4* aq = Aq + cb;
    const unsigned* as_ = As + cb;
    uint4* bq = Bq + cb;
    unsigned* bs = Bs + cb;
    const int h0 = hc * HR2;

    uint4 fq[9]; unsigned fs[9];
    const __half2 z = __float2half2_rn(0.f);
    __half2 S0 = z, S1 = z, S2 = z, S3 = z, S4 = z;
#pragma unroll
    for (int j = 0; j < 9; ++j) {
        int hh = h0 - 4 + j;
        uint4 q = make_uint4(0u, 0u, 0u, 0u); unsigned sv = 0u;
        if ((unsigned)hh < (unsigned)H_) {
            q = aq[(size_t)hh * WP_]; sv = as_[(size_t)hh * WP_];
        }
        fq[j] = q; fs[j] = sv;
        S0 = __hadd2(S0, u2h(q.x)); S1 = __hadd2(S1, u2h(q.y));
        S2 = __hadd2(S2, u2h(q.z)); S3 = __hadd2(S3, u2h(q.w));
        S4 = __hadd2(S4, u2h(sv));
    }
#pragma unroll
    for (int i = 0; i < HR2; ++i) {
        const int h = h0 + i;
        bq[(size_t)h * WP_] = make_uint4(h2u(S0), h2u(S1), h2u(S2), h2u(S3));
        bs[(size_t)h * WP_] = h2u(S4);
        if (i + 1 < HR2) {
            int hh = h + 5;
            uint4 q = make_uint4(0u, 0u, 0u, 0u); unsigned sv = 0u;
            if (hh < H_) { q = aq[(size_t)hh * WP_]; sv = as_[(size_t)hh * WP_]; }
            S0 = __hadd2(__hsub2(S0, u2h(fq[0].x)), u2h(q.x));
            S1 = __hadd2(__hsub2(S1, u2h(fq[0].y)), u2h(q.y));
            S2 = __hadd2(__hsub2(S2, u2h(fq[0].z)), u2h(q.z));
            S3 = __hadd2(__hsub2(S3, u2h(fq[0].w)), u2h(q.w));
            S4 = __hadd2(__hsub2(S4, u2h(fs[0])), u2h(sv));
#pragma unroll
            for (int j = 0; j < 8; ++j) { fq[j] = fq[j + 1]; fs[j] = fs[j + 1]; }
            fq[8] = q; fs[8] = sv;
        }
    }
}

// ------- pass3: D-axis box sum + cc + reduce, f32 state (R9) ---------------
__global__ __launch_bounds__(256) void ncc_pass3(const uint4* __restrict__ Bq,
                                                 const unsigned* __restrict__ Bs,
                                                 float* __restrict__ acc) {
    const int pp = (blockIdx.x % (HWP_ / 256)) * 256 + threadIdx.x;
    const int d0 = (blockIdx.x / (HWP_ / 256)) * CH3;
    const uint4* bq = Bq + pp;
    const unsigned* bs = Bs + pp;

    uint4 fq[9]; unsigned fs[9];
    float2 S[5] = {{0,0},{0,0},{0,0},{0,0},{0,0}};
#pragma unroll
    for (int j = 0; j < 9; ++j) {
        int dd = d0 - 4 + j;
        uint4 q = make_uint4(0u, 0u, 0u, 0u); unsigned sv = 0u;
        if ((unsigned)dd < (unsigned)D_) {
            q = bq[(size_t)dd * HWP_]; sv = bs[(size_t)dd * HWP_];
        }
        fq[j] = q; fs[j] = sv;
        addU(S, q, sv);
    }
    float sum = 0.f;
#pragma unroll
    for (int i = 0; i < CH3; ++i) {
        {
            float cr = S[4].x - S[1].x * S[0].x * WIN_INV;
            float Iv = S[2].x - S[0].x * S[0].x * WIN_INV;
            float Jv = S[3].x - S[1].x * S[1].x * WIN_INV;
            sum += cr * cr / (Iv * Jv + 1e-5f);
        }
        {
            float cr = S[4].y - S[1].y * S[0].y * WIN_INV;
            float Iv = S[2].y - S[0].y * S[0].y * WIN_INV;
            float Jv = S[3].y - S[1].y * S[1].y * WIN_INV;
            sum += cr * cr / (Iv * Jv + 1e-5f);
        }
        if (i + 1 < CH3) {
            int dl = d0 + i + 5;
            uint4 q = make_uint4(0u, 0u, 0u, 0u); unsigned sv = 0u;
            if (dl < D_) { q = bq[(size_t)dl * HWP_]; sv = bs[(size_t)dl * HWP_]; }
            subU(S, fq[0], fs[0]);
            addU(S, q, sv);
#pragma unroll
            for (int j = 0; j < 8; ++j) { fq[j] = fq[j + 1]; fs[j] = fs[j + 1]; }
            fq[8] = q; fs[8] = sv;
        }
    }

    for (int off = 32; off; off >>= 1) sum += __shfl_down(sum, off, 64);
    __shared__ float wsum[4];
    const int lane = threadIdx.x & 63, wv = threadIdx.x >> 6;
    if (lane == 0) wsum[wv] = sum;
    __syncthreads();
    if (threadIdx.x == 0)
        atomicAdd(acc, wsum[0] + wsum[1] + wsum[2] + wsum[3]);
}

__global__ void ncc_finalize(const float* __restrict__ acc,
                             float* __restrict__ out) {
    out[0] = 1.0f - acc[0] * (1.0f / (float)N_);
}

extern "C" void kernel_launch(void* const* d_in, const int* in_sizes, int n_in,
                              void* d_out, int out_size, void* d_ws, size_t ws_size,
                              hipStream_t stream) {
    const float* I = (const float*)d_in[0];   // y_true
    const float* J = (const float*)d_in[1];   // y_pred
    char* w = (char*)d_ws;
    uint4* Aq = (uint4*)w;                                 // 31.46 MB
    uint4* Bq = (uint4*)(w + (size_t)NP_ * 16);            // 31.46 MB
    unsigned* As = (unsigned*)(w + (size_t)NP_ * 32);      // 7.86 MB
    unsigned* Bs = (unsigned*)(w + (size_t)NP_ * 36);      // 7.86 MB
    float* acc = (float*)(w + (size_t)NP_ * 40);
    float* out = (float*)d_out;

    ncc_pass1<<<D_ * H_ / 2, 256, 0, stream>>>(I, J, Aq, As, acc);
    ncc_pass2<<<(D_ * 16 * WP_) / 256, 256, 0, stream>>>(Aq, As, Bq, Bs);
    ncc_pass3<<<(HWP_ / 256) * (D_ / CH3), 256, 0, stream>>>(Bq, Bs, acc);
    ncc_finalize<<<1, 1, 0, stream>>>(acc, out);
}

// Round 12
// 53.084 us; speedup vs baseline: 1.4139x; 1.0385x over previous
//
#include <hip/hip_runtime.h>
#include <hip/hip_fp16.h>

// NCC (local normalized cross-correlation) loss, 9x9x9 window, zero-pad.
// Volume: [1,1,128,160,192] f32. Output: scalar f32 = 1 - mean(cc).
//
// R12 = R11 + XCD-chunked block swizzles (halo re-reads -> same-XCD L2 hits):
//   pass1: W-sums -> Aq/As (packed stores).                       [R9]
//   pass2: H-sums Aq/As -> Bq/Bs, pk-fp16 FIFO, runs of 10.
//          Chunked swizzle: each XCD owns 16 whole d-slices.
//   pass3: D-sums + cc + reduce, f32 state + packed FIFO, runs of 8.
//          Grid reordered pp-major (k fast) + chunked swizzle: all 8
//          d-chunks of a pp-range share one XCD's L2.
//   finalize: separate kernel.
// Layout per pixel-pair: ch0..3 = uint4 (4x half2), ch4 = u32.
// ws: Aq 31.5MB | Bq 31.5MB | As 7.9MB | Bs 7.9MB | acc.

#define D_ 128
#define H_ 160
#define W_ 192
#define WP_ (W_ / 2)               // 96 pairs per line
#define HW_ (H_ * W_)
#define HWP_ (HW_ / 2)             // 15360 pairs per d-slice
#define N_ (D_ * H_ * W_)
#define NP_ (N_ / 2)               // 1,966,080 pairs total
#define WIN_INV (1.0f / 729.0f)
#define HR2 10                     // h-run length in pass2 (16 chunks)
#define CH3 8                      // d-run length in pass3 (16 chunks)
#define NBLK2 ((D_ * 16 * WP_) / 256)          // 768
#define NBLK3 ((HWP_ / 256) * (D_ / CH3))      // 960
#define NXCD 8

union U32H2 { unsigned u; __half2 h; };
__device__ __forceinline__ __half2 u2h(unsigned u) { U32H2 x; x.u = u; return x.h; }
__device__ __forceinline__ unsigned h2u(__half2 h) { U32H2 x; x.h = h; return x.u; }
__device__ __forceinline__ unsigned pack2(float x, float y) {
    return h2u(__float22half2_rn(make_float2(x, y)));
}
__device__ __forceinline__ float2 unpack2(unsigned u) {
    return __half22float2(u2h(u));
}

__device__ __forceinline__ void addU(float2 S[5], const uint4& q, unsigned sv) {
    float2 v0 = unpack2(q.x), v1 = unpack2(q.y), v2 = unpack2(q.z),
           v3 = unpack2(q.w), v4 = unpack2(sv);
    S[0].x += v0.x; S[0].y += v0.y;
    S[1].x += v1.x; S[1].y += v1.y;
    S[2].x += v2.x; S[2].y += v2.y;
    S[3].x += v3.x; S[3].y += v3.y;
    S[4].x += v4.x; S[4].y += v4.y;
}
__device__ __forceinline__ void subU(float2 S[5], const uint4& q, unsigned sv) {
    float2 v0 = unpack2(q.x), v1 = unpack2(q.y), v2 = unpack2(q.z),
           v3 = unpack2(q.w), v4 = unpack2(sv);
    S[0].x -= v0.x; S[0].y -= v0.y;
    S[1].x -= v1.x; S[1].y -= v1.y;
    S[2].x -= v2.x; S[2].y -= v2.y;
    S[3].x -= v3.x; S[3].y -= v3.y;
    S[4].x -= v4.x; S[4].y -= v4.y;
}

// ---------------- pass1: W-axis box sum -> packed A ------------------------
__global__ __launch_bounds__(256) void ncc_pass1(const float* __restrict__ I,
                                                 const float* __restrict__ J,
                                                 uint4* __restrict__ Aq,
                                                 unsigned* __restrict__ As,
                                                 float* __restrict__ acc) {
    __shared__ float sI[2 * W_];
    __shared__ float sJ[2 * W_];
    const int t = threadIdx.x;
    const int line0 = blockIdx.x * 2;
    const int base = line0 * W_;
    sI[t] = I[base + t];
    sJ[t] = J[base + t];
    if (t < 2 * W_ - 256) { sI[t + 256] = I[base + t + 256]; sJ[t + 256] = J[base + t + 256]; }
    if (blockIdx.x == 0 && t == 0) *acc = 0.0f;
    __syncthreads();
    if (t >= 2 * WP_) return;
    const int ll = t / WP_;
    const int wp = t % WP_;
    const int w0 = 2 * wp;
    const float* a_ = sI + ll * W_;
    const float* b_ = sJ + ll * W_;
    float s1a = 0, s2a = 0, s3a = 0, s4a = 0, s5a = 0;
    float s1b = 0, s2b = 0, s3b = 0, s4b = 0, s5b = 0;
#pragma unroll
    for (int j = -4; j <= 5; ++j) {
        int idx = w0 + j;
        float a = 0.f, b = 0.f;
        if (idx >= 0 && idx < W_) { a = a_[idx]; b = b_[idx]; }
        float p3 = a * a, p4 = b * b, p5 = a * b;
        if (j <= 4) { s1a += a; s2a += b; s3a += p3; s4a += p4; s5a += p5; }
        if (j >= -3) { s1b += a; s2b += b; s3b += p3; s4b += p4; s5b += p5; }
    }
    const size_t o = (size_t)(line0 + ll) * WP_ + wp;
    Aq[o] = make_uint4(pack2(s1a, s1b), pack2(s2a, s2b),
                       pack2(s3a, s3b), pack2(s4a, s4b));
    As[o] = pack2(s5a, s5b);
}

// ---------------- pass2: H-axis box sum, pk-fp16 FIFO, XCD-chunked ---------
__global__ __launch_bounds__(256) void ncc_pass2(const uint4* __restrict__ Aq,
                                                 const unsigned* __restrict__ As,
                                                 uint4* __restrict__ Bq,
                                                 unsigned* __restrict__ Bs) {
    // chunked swizzle: XCD x runs orig in [x*96, (x+1)*96) = 16 whole d-slices
    const int orig = (blockIdx.x % NXCD) * (NBLK2 / NXCD) + blockIdx.x / NXCD;
    const int t = orig * 256 + threadIdx.x;         // < 128*16*96 = 196608
    const int wp = t % WP_;
    const int r = t / WP_;
    const int hc = r & 15;
    const int d = r >> 4;
    const size_t cb = (size_t)d * (H_ * WP_) + wp;
    const uint4* aq = Aq + cb;
    const unsigned* as_ = As + cb;
    uint4* bq = Bq + cb;
    unsigned* bs = Bs + cb;
    const int h0 = hc * HR2;

    uint4 fq[9]; unsigned fs[9];
    const __half2 z = __float2half2_rn(0.f);
    __half2 S0 = z, S1 = z, S2 = z, S3 = z, S4 = z;
#pragma unroll
    for (int j = 0; j < 9; ++j) {
        int hh = h0 - 4 + j;
        uint4 q = make_uint4(0u, 0u, 0u, 0u); unsigned sv = 0u;
        if ((unsigned)hh < (unsigned)H_) {
            q = aq[(size_t)hh * WP_]; sv = as_[(size_t)hh * WP_];
        }
        fq[j] = q; fs[j] = sv;
        S0 = __hadd2(S0, u2h(q.x)); S1 = __hadd2(S1, u2h(q.y));
        S2 = __hadd2(S2, u2h(q.z)); S3 = __hadd2(S3, u2h(q.w));
        S4 = __hadd2(S4, u2h(sv));
    }
#pragma unroll
    for (int i = 0; i < HR2; ++i) {
        const int h = h0 + i;
        bq[(size_t)h * WP_] = make_uint4(h2u(S0), h2u(S1), h2u(S2), h2u(S3));
        bs[(size_t)h * WP_] = h2u(S4);
        if (i + 1 < HR2) {
            int hh = h + 5;
            uint4 q = make_uint4(0u, 0u, 0u, 0u); unsigned sv = 0u;
            if (hh < H_) { q = aq[(size_t)hh * WP_]; sv = as_[(size_t)hh * WP_]; }
            S0 = __hadd2(__hsub2(S0, u2h(fq[0].x)), u2h(q.x));
            S1 = __hadd2(__hsub2(S1, u2h(fq[0].y)), u2h(q.y));
            S2 = __hadd2(__hsub2(S2, u2h(fq[0].z)), u2h(q.z));
            S3 = __hadd2(__hsub2(S3, u2h(fq[0].w)), u2h(q.w));
            S4 = __hadd2(__hsub2(S4, u2h(fs[0])), u2h(sv));
#pragma unroll
            for (int j = 0; j < 8; ++j) { fq[j] = fq[j + 1]; fs[j] = fs[j + 1]; }
            fq[8] = q; fs[8] = sv;
        }
    }
}

// ------- pass3: D-axis box sum + cc + reduce, pp-major + XCD-chunked -------
__global__ __launch_bounds__(256) void ncc_pass3(const uint4* __restrict__ Bq,
                                                 const unsigned* __restrict__ Bs,
                                                 float* __restrict__ acc) {
    // pp-major (k fast) then chunked swizzle: an XCD holds all 8 d-chunks
    // of its pp-ranges -> warm-up slices of chunk k overlap chunk k-1's
    // steady reads in the same L2.
    const int orig = (blockIdx.x % NXCD) * (NBLK3 / NXCD) + blockIdx.x / NXCD;
    const int k = orig & 7;                        // d-chunk (fast)
    const int ppBlk = orig >> 3;                   // pp-group (slow)
    const int pp = ppBlk * 256 + threadIdx.x;
    const int d0 = k * CH3;
    const uint4* bq = Bq + pp;
    const unsigned* bs = Bs + pp;

    uint4 fq[9]; unsigned fs[9];
    float2 S[5] = {{0,0},{0,0},{0,0},{0,0},{0,0}};
#pragma unroll
    for (int j = 0; j < 9; ++j) {
        int dd = d0 - 4 + j;
        uint4 q = make_uint4(0u, 0u, 0u, 0u); unsigned sv = 0u;
        if ((unsigned)dd < (unsigned)D_) {
            q = bq[(size_t)dd * HWP_]; sv = bs[(size_t)dd * HWP_];
        }
        fq[j] = q; fs[j] = sv;
        addU(S, q, sv);
    }
    float sum = 0.f;
#pragma unroll
    for (int i = 0; i < CH3; ++i) {
        {
            float cr = S[4].x - S[1].x * S[0].x * WIN_INV;
            float Iv = S[2].x - S[0].x * S[0].x * WIN_INV;
            float Jv = S[3].x - S[1].x * S[1].x * WIN_INV;
            sum += cr * cr / (Iv * Jv + 1e-5f);
        }
        {
            float cr = S[4].y - S[1].y * S[0].y * WIN_INV;
            float Iv = S[2].y - S[0].y * S[0].y * WIN_INV;
            float Jv = S[3].y - S[1].y * S[1].y * WIN_INV;
            sum += cr * cr / (Iv * Jv + 1e-5f);
        }
        if (i + 1 < CH3) {
            int dl = d0 + i + 5;
            uint4 q = make_uint4(0u, 0u, 0u, 0u); unsigned sv = 0u;
            if (dl < D_) { q = bq[(size_t)dl * HWP_]; sv = bs[(size_t)dl * HWP_]; }
            subU(S, fq[0], fs[0]);
            addU(S, q, sv);
#pragma unroll
            for (int j = 0; j < 8; ++j) { fq[j] = fq[j + 1]; fs[j] = fs[j + 1]; }
            fq[8] = q; fs[8] = sv;
        }
    }

    for (int off = 32; off; off >>= 1) sum += __shfl_down(sum, off, 64);
    __shared__ float wsum[4];
    const int lane = threadIdx.x & 63, wv = threadIdx.x >> 6;
    if (lane == 0) wsum[wv] = sum;
    __syncthreads();
    if (threadIdx.x == 0)
        atomicAdd(acc, wsum[0] + wsum[1] + wsum[2] + wsum[3]);
}

__global__ void ncc_finalize(const float* __restrict__ acc,
                             float* __restrict__ out) {
    out[0] = 1.0f - acc[0] * (1.0f / (float)N_);
}

extern "C" void kernel_launch(void* const* d_in, const int* in_sizes, int n_in,
                              void* d_out, int out_size, void* d_ws, size_t ws_size,
                              hipStream_t stream) {
    const float* I = (const float*)d_in[0];   // y_true
    const float* J = (const float*)d_in[1];   // y_pred
    char* w = (char*)d_ws;
    uint4* Aq = (uint4*)w;                                 // 31.46 MB
    uint4* Bq = (uint4*)(w + (size_t)NP_ * 16);            // 31.46 MB
    unsigned* As = (unsigned*)(w + (size_t)NP_ * 32);      // 7.86 MB
    unsigned* Bs = (unsigned*)(w + (size_t)NP_ * 36);      // 7.86 MB
    float* acc = (float*)(w + (size_t)NP_ * 40);
    float* out = (float*)d_out;

    ncc_pass1<<<D_ * H_ / 2, 256, 0, stream>>>(I, J, Aq, As, acc);
    ncc_pass2<<<NBLK2, 256, 0, stream>>>(Aq, As, Bq, Bs);
    ncc_pass3<<<NBLK3, 256, 0, stream>>>(Bq, Bs, acc);
    ncc_finalize<<<1, 1, 0, stream>>>(acc, out);
}